// Round 3
// baseline (251.620 us; speedup 1.0000x reference)
//
#include <hip/hip_runtime.h>
#include <hip/hip_bf16.h>
#include <hip/hip_cooperative_groups.h>

namespace cg = cooperative_groups;

// MFMA fragment types (cdna_hip_programming.md §3)
typedef __attribute__((ext_vector_type(8))) short bf16x8;
typedef __attribute__((ext_vector_type(4))) float f32x4;

#define BATCH 64
#define SEQ   128
#define EMB   256
#define ENC   256
#define NIN   64
#define NSL   128

// packed-weight geometry in d_ws (bf16, B-fragment-major [kblk][n][j]):
//   w1p  : [32][256][8] (slot_enc_W)  off 0
//   w2p  : [32][128][8] (slot_dec_W)  off 65536
//   dw1p : [32][256][8] (doc_enc_W)   off 98304
//   dw2p : [32][ 64][8] (doc_dec_W)   off 163840
// total pack items = 8192 + 4096 + 8192 + 2048 = 22528 = 512 blocks * 44
#define W1P_OFF   0
#define W2P_OFF   65536
#define DW1P_OFF  98304
#define DW2P_OFF  163840
#define NPACK     22528

static __device__ __forceinline__ void pack_item(
    int item,
    const float* __restrict__ slot_enc_W, const float* __restrict__ slot_dec_W,
    const float* __restrict__ doc_enc_W,  const float* __restrict__ doc_dec_W,
    __hip_bfloat16* __restrict__ ws)
{
    const float* W; int ncols; __hip_bfloat16* dst; int idx;
    if (item < 8192)       { W = slot_enc_W; ncols = 256; dst = ws + W1P_OFF;  idx = item; }
    else if (item < 12288) { W = slot_dec_W; ncols = 128; dst = ws + W2P_OFF;  idx = item - 8192; }
    else if (item < 20480) { W = doc_enc_W;  ncols = 256; dst = ws + DW1P_OFF; idx = item - 12288; }
    else                   { W = doc_dec_W;  ncols = 64;  dst = ws + DW2P_OFF; idx = item - 20480; }
    const int n  = idx % ncols;
    const int bk = idx / ncols;
    union { bf16x8 v; __hip_bfloat16 h[8]; } u;
    #pragma unroll
    for (int j = 0; j < 8; ++j)
        u.h[j] = __float2bfloat16(W[(bk * 8 + j) * ncols + n]);
    *(bf16x8*)(dst + (size_t)idx * 8) = u.v;
}

static __device__ __forceinline__ bf16x8 cvt8(const float4 lo, const float4 hi) {
    union { bf16x8 v; __hip_bfloat16 h[8]; } u;
    u.h[0] = __float2bfloat16(lo.x); u.h[1] = __float2bfloat16(lo.y);
    u.h[2] = __float2bfloat16(lo.z); u.h[3] = __float2bfloat16(lo.w);
    u.h[4] = __float2bfloat16(hi.x); u.h[5] = __float2bfloat16(hi.y);
    u.h[6] = __float2bfloat16(hi.z); u.h[7] = __float2bfloat16(hi.w);
    return u.v;
}

// ---------------------------------------------------------------------------
// ONE cooperative kernel, 512 blocks (2/CU co-resident).
//   phase A (pre grid-sync, overlapped):
//     - 44 threads/block pack one weight-fragment-set each (global bf16 ws)
//     - all blocks gather their 16 token rows -> bf16 LDS tile [16][264]
//     - doc blocks (logical blk&7==0) additionally gather+mean their batch's
//       128 token rows -> sent[256] (fp32, in the lds_we region)
//   grid.sync()
//   phase B:
//     - doc blocks: MFMA doc encoder/decoder (broadcast-A trick) -> out_intent
//     - all blocks: slots stage 1 (MFMA, relu -> lds_we), stage 2 (MFMA),
//       epilogue (+bias +one-hot row) -> out_slots
// XCD-chunked swizzle: logical blk = (bid&7)*64 + bid>>3, so the doc block
// and the 8 slots blocks of one batch share an XCD -> doc re-read is L2-hit.
// ---------------------------------------------------------------------------
__global__ __launch_bounds__(256) void fused_kernel(
    const int*   __restrict__ token_ids,
    const int*   __restrict__ all_intents,
    const float* __restrict__ emb_table,
    const float* __restrict__ doc_enc_W,
    const float* __restrict__ doc_enc_b,
    const float* __restrict__ slot_enc_W,
    const float* __restrict__ slot_enc_b,
    const float* __restrict__ doc_dec_W,
    const float* __restrict__ doc_dec_b,
    const float* __restrict__ slot_dec_W,   // [320][128], fp32 (one-hot rows)
    const float* __restrict__ slot_dec_b,
    __hip_bfloat16* __restrict__ ws,        // packed weights (bf16)
    float* __restrict__ out_intent,         // fp32 [64][64]
    float* __restrict__ out_slots)          // fp32 [8192][128]
{
    __shared__ __align__(16) char smem[2 * 16 * 264 * 2];   // 16.9 KB

    const int bid  = blockIdx.x;
    const int blk  = ((bid & 7) << 6) | (bid >> 3);   // bijective XCD-chunk swizzle
    const int wave = threadIdx.x >> 6;
    const int lane = threadIdx.x & 63;
    const int l16  = lane & 15;
    const int quad = lane >> 4;

    __hip_bfloat16* lds_emb = (__hip_bfloat16*)smem;             // [16][264]
    __hip_bfloat16* lds_we  = (__hip_bfloat16*)(smem + 8448);    // [16][264]
    // doc scratch lives in the lds_we region during phase A / doc compute:
    float* doc_red  = (float*)(smem + 8448);          // [4][256]
    float* doc_sent = (float*)(smem + 8448 + 4096);   // [256]
    float* doc_senc = (float*)(smem + 8448 + 5120);   // [256]

    const bool docb = (blk & 7) == 0;
    const int  row0 = blk * 16;

    // ================= phase A =================
    // weight packing: 44 threads/block, one fragment-set each, overlapped
    // with the token gathers below.
    if (threadIdx.x < 44)
        pack_item(bid * 44 + threadIdx.x,
                  slot_enc_W, slot_dec_W, doc_enc_W, doc_dec_W, ws);

    // slots gather: 16 token rows -> lds_emb. Each wave-iteration reads one
    // full 1 KB row coalesced.
    #pragma unroll
    for (int i = 0; i < 4; ++i) {
        const int idx = i * 256 + threadIdx.x;    // 0..1023
        const int r   = idx >> 6;                 // row 0..15
        const int c4  = idx & 63;                 // float4 within row
        const long tok = token_ids[row0 + r];
        const float4 v = *(const float4*)(emb_table + tok * EMB + c4 * 4);
        union { ushort4 s; __hip_bfloat16 h[4]; } u;
        u.h[0] = __float2bfloat16(v.x); u.h[1] = __float2bfloat16(v.y);
        u.h[2] = __float2bfloat16(v.z); u.h[3] = __float2bfloat16(v.w);
        *(ushort4*)(lds_emb + r * 264 + c4 * 4) = u.s;
    }

    if (docb) {
        // doc gather + mean for batch b = blk>>3 (rows are L2-hot: the same
        // XCD's slots blocks just gathered them)
        const int b  = blk >> 3;
        const int* toks = token_ids + b * SEQ;
        float4 accv = make_float4(0.f, 0.f, 0.f, 0.f);
        #pragma unroll 8
        for (int i = 0; i < 32; ++i) {
            const long tok = toks[wave * 32 + i];
            const float4 v = *(const float4*)(emb_table + tok * EMB + lane * 4);
            accv.x += v.x; accv.y += v.y; accv.z += v.z; accv.w += v.w;
        }
        *(float4*)(&doc_red[wave * 256 + lane * 4]) = accv;
        __syncthreads();
        doc_sent[threadIdx.x] =
            (doc_red[threadIdx.x] + doc_red[256 + threadIdx.x] +
             doc_red[512 + threadIdx.x] + doc_red[768 + threadIdx.x]) * (1.0f / 128.0f);
    }

    if (threadIdx.x < 44) __threadfence();   // packed-weight visibility
    cg::this_grid().sync();

    const __hip_bfloat16* w1p  = ws + W1P_OFF;
    const __hip_bfloat16* w2p  = ws + W2P_OFF;
    const __hip_bfloat16* dw1p = ws + DW1P_OFF;
    const __hip_bfloat16* dw2p = ws + DW2P_OFF;

    // ================= phase B: doc compute (doc blocks only) =================
    if (docb) {
        const int b = blk >> 3;

        // doc encoder: senc = relu(sent @ W + b); wave owns 64 cols.
        // A rows all identical (sent broadcast) -> read acc reg 0.
        f32x4 dacc[4];
        #pragma unroll
        for (int nt = 0; nt < 4; ++nt) dacc[nt] = (f32x4){0.f, 0.f, 0.f, 0.f};

        #pragma unroll
        for (int ks = 0; ks < 8; ++ks) {
            const float* sp = doc_sent + ks * 32 + quad * 8;
            const bf16x8 a = cvt8(*(const float4*)sp, *(const float4*)(sp + 4));
            const int kblk = ks * 4 + quad;
            #pragma unroll
            for (int nt = 0; nt < 4; ++nt) {
                const int n = wave * 64 + nt * 16 + l16;
                const bf16x8 bf = *(const bf16x8*)(dw1p + ((size_t)kblk * 256 + n) * 8);
                dacc[nt] = __builtin_amdgcn_mfma_f32_16x16x32_bf16(a, bf, dacc[nt], 0, 0, 0);
            }
        }
        if (quad == 0) {
            #pragma unroll
            for (int nt = 0; nt < 4; ++nt) {
                const int col = wave * 64 + nt * 16 + l16;
                doc_senc[col] = fmaxf(dacc[nt][0] + doc_enc_b[col], 0.f);
            }
        }
        __syncthreads();

        // doc decoder: intent = senc @ Wd + b; wave owns 16 cols
        f32x4 iacc = (f32x4){0.f, 0.f, 0.f, 0.f};
        #pragma unroll
        for (int ks = 0; ks < 8; ++ks) {
            const float* sp = doc_senc + ks * 32 + quad * 8;
            const bf16x8 a = cvt8(*(const float4*)sp, *(const float4*)(sp + 4));
            const int kblk = ks * 4 + quad;
            const int n = wave * 16 + l16;
            const bf16x8 bf = *(const bf16x8*)(dw2p + ((size_t)kblk * 64 + n) * 8);
            iacc = __builtin_amdgcn_mfma_f32_16x16x32_bf16(a, bf, iacc, 0, 0, 0);
        }
        if (quad == 0)
            out_intent[b * NIN + wave * 16 + l16] = iacc[0] + doc_dec_b[wave * 16 + l16];
        __syncthreads();   // senc/sent reads done before stage 1 reuses lds_we
    }

    // ================= phase B: slots (all blocks) =================
    // stage 1: word_enc = relu(emb @ W1 + b1); wave owns 64 N-cols
    f32x4 acc[4];
    #pragma unroll
    for (int nt = 0; nt < 4; ++nt) acc[nt] = (f32x4){0.f, 0.f, 0.f, 0.f};

    const int nbase1 = wave * 64;
    #pragma unroll
    for (int ks = 0; ks < 8; ++ks) {
        const bf16x8 a0 = *(const bf16x8*)(lds_emb + l16 * 264 + ks * 32 + quad * 8);
        const int kblk = ks * 4 + quad;
        #pragma unroll
        for (int nt = 0; nt < 4; ++nt) {
            const int n = nbase1 + nt * 16 + l16;
            const bf16x8 bf = *(const bf16x8*)(w1p + ((size_t)kblk * 256 + n) * 8);
            acc[nt] = __builtin_amdgcn_mfma_f32_16x16x32_bf16(a0, bf, acc[nt], 0, 0, 0);
        }
    }

    #pragma unroll
    for (int nt = 0; nt < 4; ++nt) {
        const int col = nbase1 + nt * 16 + l16;
        const float bias = slot_enc_b[col];
        #pragma unroll
        for (int r = 0; r < 4; ++r) {
            const int row = quad * 4 + r;   // D: col=lane&15, row=quad*4+reg
            lds_we[row * 264 + col] =
                __float2bfloat16(fmaxf(acc[nt][r] + bias, 0.f));
        }
    }
    __syncthreads();

    // stage 2: slots = word_enc @ W2; wave owns 32 N-cols
    f32x4 acc2[2];
    #pragma unroll
    for (int nt = 0; nt < 2; ++nt) acc2[nt] = (f32x4){0.f, 0.f, 0.f, 0.f};

    const int nbase2 = wave * 32;
    #pragma unroll
    for (int ks = 0; ks < 8; ++ks) {
        const bf16x8 a0 = *(const bf16x8*)(lds_we + l16 * 264 + ks * 32 + quad * 8);
        const int kblk = ks * 4 + quad;
        #pragma unroll
        for (int nt = 0; nt < 2; ++nt) {
            const int n = nbase2 + nt * 16 + l16;
            const bf16x8 bf = *(const bf16x8*)(w2p + ((size_t)kblk * 128 + n) * 8);
            acc2[nt] = __builtin_amdgcn_mfma_f32_16x16x32_bf16(a0, bf, acc2[nt], 0, 0, 0);
        }
    }

    // epilogue: + slot_dec_b + slot_dec_W[256 + intent[b]] row, fp32 store
    const int intent = all_intents[blk >> 3];
    const float* hotrow = slot_dec_W + (long)(256 + intent) * NSL;

    #pragma unroll
    for (int nt = 0; nt < 2; ++nt) {
        const int col = nbase2 + nt * 16 + l16;
        const float add = slot_dec_b[col] + hotrow[col];
        #pragma unroll
        for (int r = 0; r < 4; ++r) {
            const int row = quad * 4 + r;
            out_slots[(long)(row0 + row) * NSL + col] = acc2[nt][r] + add;
        }
    }
}

// ---------------------------------------------------------------------------
extern "C" void kernel_launch(void* const* d_in, const int* in_sizes, int n_in,
                              void* d_out, int out_size, void* d_ws, size_t ws_size,
                              hipStream_t stream) {
    const int*   token_ids   = (const int*)d_in[0];
    const int*   all_intents = (const int*)d_in[1];
    const float* emb_table   = (const float*)d_in[2];
    const float* doc_enc_W   = (const float*)d_in[3];
    const float* doc_enc_b   = (const float*)d_in[4];
    const float* slot_enc_W  = (const float*)d_in[5];
    const float* slot_enc_b  = (const float*)d_in[6];
    const float* doc_dec_W   = (const float*)d_in[7];
    const float* doc_dec_b   = (const float*)d_in[8];
    const float* slot_dec_W  = (const float*)d_in[9];
    const float* slot_dec_b  = (const float*)d_in[10];

    __hip_bfloat16* ws = (__hip_bfloat16*)d_ws;
    float* out        = (float*)d_out;
    float* out_intent = out;                    // fp32 [64][64]
    float* out_slots  = out + BATCH * NIN;      // fp32 [8192][128]

    void* args[] = {
        (void*)&token_ids, (void*)&all_intents, (void*)&emb_table,
        (void*)&doc_enc_W, (void*)&doc_enc_b,
        (void*)&slot_enc_W, (void*)&slot_enc_b,
        (void*)&doc_dec_W, (void*)&doc_dec_b,
        (void*)&slot_dec_W, (void*)&slot_dec_b,
        (void*)&ws, (void*)&out_intent, (void*)&out_slots,
    };
    hipLaunchCooperativeKernel((const void*)fused_kernel,
                               dim3(512), dim3(256), args, 0, stream);
}

// Round 4
// 195.805 us; speedup vs baseline: 1.2851x; 1.2851x over previous
//
#include <hip/hip_runtime.h>
#include <hip/hip_bf16.h>

// MFMA fragment types (cdna_hip_programming.md §3)
typedef __attribute__((ext_vector_type(8))) short bf16x8;
typedef __attribute__((ext_vector_type(4))) float f32x4;

#define BATCH 64
#define SEQ   128
#define EMB   256
#define ENC   256
#define NIN   64
#define NSL   128

// packed-weight geometry in d_ws (bf16, B-fragment-major [kblk][n][j]):
//   w1p  : [32][256][8] (slot_enc_W)  off 0
//   w2p  : [32][128][8] (slot_dec_W)  off 65536
//   dw1p : [32][256][8] (doc_enc_W)   off 98304
//   dw2p : [32][ 64][8] (doc_dec_W)   off 163840
#define W1P_OFF   0
#define W2P_OFF   65536
#define DW1P_OFF  98304
#define DW2P_OFF  163840
#define NPACK     22528          // 8192 + 4096 + 8192 + 2048 = 88 blocks * 256
// byte offsets within d_ws for the doc-reduction scratch:
#define CNT_OFF_B    393216     // int cnt[64]          (zeroed by prep each run)
#define SENTP_OFF_B  524288     // float sent_part[64][8][256] (fully overwritten)

// ---------------------------------------------------------------------------
// prep: transpose fp32 row-major weights into bf16 B-fragment-major layout,
// and zero the per-batch arrival counters (workspace is re-poisoned between
// graph replays, so this must run every launch).
// ---------------------------------------------------------------------------
#define PACK(W, NCOLS, DST, IDX) {                                            \
    const int n  = (IDX) & ((NCOLS) - 1);                                     \
    const int bk = (IDX) / (NCOLS);                                           \
    union { bf16x8 v; __hip_bfloat16 h[8]; } u;                               \
    _Pragma("unroll")                                                         \
    for (int j = 0; j < 8; ++j)                                               \
        u.h[j] = __float2bfloat16((W)[(bk * 8 + j) * (NCOLS) + n]);           \
    *(bf16x8*)((DST) + (size_t)(IDX) * 8) = u.v; }

__global__ __launch_bounds__(256) void prep_kernel(
    const float* __restrict__ slot_enc_W,   // [256][256]
    const float* __restrict__ slot_dec_W,   // [320][128] (k rows 0..255 used)
    const float* __restrict__ doc_enc_W,    // [256][256]
    const float* __restrict__ doc_dec_W,    // [256][64]
    __hip_bfloat16* __restrict__ ws,
    int* __restrict__ cnt)
{
    if (blockIdx.x == 88) {                 // counter-zero block
        if (threadIdx.x < BATCH) cnt[threadIdx.x] = 0;
        return;
    }
    const int tid = blockIdx.x * 256 + threadIdx.x;   // 0..22527
    if (tid < 8192) {
        PACK(slot_enc_W, 256, ws + W1P_OFF,  tid);
    } else if (tid < 12288) {
        PACK(slot_dec_W, 128, ws + W2P_OFF,  tid - 8192);
    } else if (tid < 20480) {
        PACK(doc_enc_W,  256, ws + DW1P_OFF, tid - 12288);
    } else {
        PACK(doc_dec_W,   64, ws + DW2P_OFF, tid - 20480);
    }
}

static __device__ __forceinline__ bf16x8 cvt8(const float4 lo, const float4 hi) {
    union { bf16x8 v; __hip_bfloat16 h[8]; } u;
    u.h[0] = __float2bfloat16(lo.x); u.h[1] = __float2bfloat16(lo.y);
    u.h[2] = __float2bfloat16(lo.z); u.h[3] = __float2bfloat16(lo.w);
    u.h[4] = __float2bfloat16(hi.x); u.h[5] = __float2bfloat16(hi.y);
    u.h[6] = __float2bfloat16(hi.z); u.h[7] = __float2bfloat16(hi.w);
    return u.v;
}

// ---------------------------------------------------------------------------
// fused kernel, 512 blocks (2/CU), 4 waves each. Per block (16 word-rows):
//   stage 0: gather 16 token rows -> bf16 LDS tile, AND accumulate the fp32
//            column-sum of those rows for free; publish the partial to
//            sent_part[b][blk&7] (agent-scope stores, deterministic slot).
//   arrival: bump cnt[b]; the 8th arriver sums the 8 partials -> sent[256],
//            then runs the doc encoder/decoder (MFMA broadcast-A trick)
//            -> out_intent[b].  No grid sync, no re-read of emb rows.
//   stage 1: word_enc = relu(emb @ W1 + b1)  (MFMA, wave owns 64 N-cols)
//   stage 2: slots = word_enc @ W2 (+bias +one-hot row) -> out_slots
// ---------------------------------------------------------------------------
__global__ __launch_bounds__(256) void fused_kernel(
    const int*   __restrict__ token_ids,
    const int*   __restrict__ all_intents,
    const float* __restrict__ emb_table,
    const float* __restrict__ doc_enc_b,
    const float* __restrict__ slot_enc_b,
    const float* __restrict__ doc_dec_b,
    const float* __restrict__ slot_dec_W,   // [320][128], fp32 (one-hot rows)
    const float* __restrict__ slot_dec_b,
    const __hip_bfloat16* __restrict__ ws,  // packed weights (bf16)
    float* __restrict__ sent_part,          // [64][8][256] fp32
    int*   __restrict__ cnt,                // [64]
    float* __restrict__ out_intent,         // fp32 [64][64]
    float* __restrict__ out_slots)          // fp32 [8192][128]
{
    __shared__ __align__(16) char smem[2 * 16 * 264 * 2];   // 16.9 KB
    __shared__ int lds_flag;

    const int blk  = blockIdx.x;
    const int wave = threadIdx.x >> 6;
    const int lane = threadIdx.x & 63;
    const int l16  = lane & 15;
    const int quad = lane >> 4;
    const int t    = threadIdx.x;

    __hip_bfloat16* lds_emb = (__hip_bfloat16*)smem;             // [16][264]
    __hip_bfloat16* lds_we  = (__hip_bfloat16*)(smem + 8448);    // [16][264]
    float* red      = (float*)(smem + 8448);           // [4][256] (pre-stage1)
    float* doc_sent = (float*)(smem + 8448 + 4096);    // [256]
    float* doc_senc = (float*)(smem + 8448 + 5120);    // [256]

    const int row0 = blk * 16;
    const int b    = blk >> 3;       // batch of this block's rows
    const int sub  = blk & 7;        // which eighth of the batch

    const __hip_bfloat16* w1p  = ws + W1P_OFF;
    const __hip_bfloat16* w2p  = ws + W2P_OFF;
    const __hip_bfloat16* dw1p = ws + DW1P_OFF;
    const __hip_bfloat16* dw2p = ws + DW2P_OFF;

    // ---------------- stage 0: gather + free fp32 column-sum ----------
    // thread t covers column-quad c4 = t&63 across rows {wave, wave+4, wave+8, wave+12}
    float4 accv = make_float4(0.f, 0.f, 0.f, 0.f);
    #pragma unroll
    for (int i = 0; i < 4; ++i) {
        const int idx = i * 256 + t;              // 0..1023
        const int r   = idx >> 6;                 // row 0..15
        const int c4  = idx & 63;                 // float4 within row
        const long tok = token_ids[row0 + r];
        const float4 v = *(const float4*)(emb_table + tok * EMB + c4 * 4);
        accv.x += v.x; accv.y += v.y; accv.z += v.z; accv.w += v.w;
        union { ushort4 s; __hip_bfloat16 h[4]; } u;
        u.h[0] = __float2bfloat16(v.x); u.h[1] = __float2bfloat16(v.y);
        u.h[2] = __float2bfloat16(v.z); u.h[3] = __float2bfloat16(v.w);
        *(ushort4*)(lds_emb + r * 264 + c4 * 4) = u.s;
    }
    *(float4*)(&red[wave * 256 + (t & 63) * 4]) = accv;
    __syncthreads();

    // column t summed over the block's 16 rows (deterministic order)
    const float colsum = red[t] + red[256 + t] + red[512 + t] + red[768 + t];
    __hip_atomic_store(&sent_part[(b * 8 + sub) * 256 + t], colsum,
                       __ATOMIC_RELAXED, __HIP_MEMORY_SCOPE_AGENT);
    __threadfence();
    __syncthreads();
    if (t == 0) {
        const int old = __hip_atomic_fetch_add(&cnt[b], 1,
                            __ATOMIC_ACQ_REL, __HIP_MEMORY_SCOPE_AGENT);
        lds_flag = (old == 7);
    }
    __syncthreads();

    // ---------------- doc path: only the 8th arriver for batch b ----------
    if (lds_flag) {
        float s = 0.f;
        #pragma unroll
        for (int i = 0; i < 8; ++i)
            s += __hip_atomic_load(&sent_part[(b * 8 + i) * 256 + t],
                                   __ATOMIC_RELAXED, __HIP_MEMORY_SCOPE_AGENT);
        doc_sent[t] = s * (1.0f / 128.0f);
        __syncthreads();

        // doc encoder: senc = relu(sent @ W + b); wave owns 64 cols.
        // A rows all identical (sent broadcast) -> read acc reg 0.
        f32x4 dacc[4];
        #pragma unroll
        for (int nt = 0; nt < 4; ++nt) dacc[nt] = (f32x4){0.f, 0.f, 0.f, 0.f};
        #pragma unroll
        for (int ks = 0; ks < 8; ++ks) {
            const float* sp = doc_sent + ks * 32 + quad * 8;
            const bf16x8 a = cvt8(*(const float4*)sp, *(const float4*)(sp + 4));
            const int kblk = ks * 4 + quad;
            #pragma unroll
            for (int nt = 0; nt < 4; ++nt) {
                const int n = wave * 64 + nt * 16 + l16;
                const bf16x8 bf = *(const bf16x8*)(dw1p + ((size_t)kblk * 256 + n) * 8);
                dacc[nt] = __builtin_amdgcn_mfma_f32_16x16x32_bf16(a, bf, dacc[nt], 0, 0, 0);
            }
        }
        if (quad == 0) {
            #pragma unroll
            for (int nt = 0; nt < 4; ++nt) {
                const int col = wave * 64 + nt * 16 + l16;
                doc_senc[col] = fmaxf(dacc[nt][0] + doc_enc_b[col], 0.f);
            }
        }
        __syncthreads();

        // doc decoder: intent = senc @ Wd + b; wave owns 16 cols
        f32x4 iacc = (f32x4){0.f, 0.f, 0.f, 0.f};
        #pragma unroll
        for (int ks = 0; ks < 8; ++ks) {
            const float* sp = doc_senc + ks * 32 + quad * 8;
            const bf16x8 a = cvt8(*(const float4*)sp, *(const float4*)(sp + 4));
            const int kblk = ks * 4 + quad;
            const int n = wave * 16 + l16;
            const bf16x8 bf = *(const bf16x8*)(dw2p + ((size_t)kblk * 64 + n) * 8);
            iacc = __builtin_amdgcn_mfma_f32_16x16x32_bf16(a, bf, iacc, 0, 0, 0);
        }
        if (quad == 0)
            out_intent[b * NIN + wave * 16 + l16] = iacc[0] + doc_dec_b[wave * 16 + l16];
        __syncthreads();   // doc LDS reads done before stage 1 reuses lds_we
    }

    // ---------------- stage 1: word_enc = relu(emb @ W1 + b1) ----------
    f32x4 acc[4];
    #pragma unroll
    for (int nt = 0; nt < 4; ++nt) acc[nt] = (f32x4){0.f, 0.f, 0.f, 0.f};

    const int nbase1 = wave * 64;
    #pragma unroll
    for (int ks = 0; ks < 8; ++ks) {
        const bf16x8 a0 = *(const bf16x8*)(lds_emb + l16 * 264 + ks * 32 + quad * 8);
        const int kblk = ks * 4 + quad;
        #pragma unroll
        for (int nt = 0; nt < 4; ++nt) {
            const int n = nbase1 + nt * 16 + l16;
            const bf16x8 bf = *(const bf16x8*)(w1p + ((size_t)kblk * 256 + n) * 8);
            acc[nt] = __builtin_amdgcn_mfma_f32_16x16x32_bf16(a0, bf, acc[nt], 0, 0, 0);
        }
    }

    #pragma unroll
    for (int nt = 0; nt < 4; ++nt) {
        const int col = nbase1 + nt * 16 + l16;
        const float bias = slot_enc_b[col];
        #pragma unroll
        for (int r = 0; r < 4; ++r) {
            const int row = quad * 4 + r;   // D: col=lane&15, row=quad*4+reg
            lds_we[row * 264 + col] =
                __float2bfloat16(fmaxf(acc[nt][r] + bias, 0.f));
        }
    }
    __syncthreads();

    // ---------------- stage 2: slots = word_enc @ W2 ----------
    f32x4 acc2[2];
    #pragma unroll
    for (int nt = 0; nt < 2; ++nt) acc2[nt] = (f32x4){0.f, 0.f, 0.f, 0.f};

    const int nbase2 = wave * 32;
    #pragma unroll
    for (int ks = 0; ks < 8; ++ks) {
        const bf16x8 a0 = *(const bf16x8*)(lds_we + l16 * 264 + ks * 32 + quad * 8);
        const int kblk = ks * 4 + quad;
        #pragma unroll
        for (int nt = 0; nt < 2; ++nt) {
            const int n = nbase2 + nt * 16 + l16;
            const bf16x8 bf = *(const bf16x8*)(w2p + ((size_t)kblk * 128 + n) * 8);
            acc2[nt] = __builtin_amdgcn_mfma_f32_16x16x32_bf16(a0, bf, acc2[nt], 0, 0, 0);
        }
    }

    // epilogue: + slot_dec_b + slot_dec_W[256 + intent[b]] row, fp32 store
    const int intent = all_intents[b];
    const float* hotrow = slot_dec_W + (long)(256 + intent) * NSL;

    #pragma unroll
    for (int nt = 0; nt < 2; ++nt) {
        const int col = nbase2 + nt * 16 + l16;
        const float add = slot_dec_b[col] + hotrow[col];
        #pragma unroll
        for (int r = 0; r < 4; ++r) {
            const int row = quad * 4 + r;
            out_slots[(long)(row0 + row) * NSL + col] = acc2[nt][r] + add;
        }
    }
}

// ---------------------------------------------------------------------------
extern "C" void kernel_launch(void* const* d_in, const int* in_sizes, int n_in,
                              void* d_out, int out_size, void* d_ws, size_t ws_size,
                              hipStream_t stream) {
    const int*   token_ids   = (const int*)d_in[0];
    const int*   all_intents = (const int*)d_in[1];
    const float* emb_table   = (const float*)d_in[2];
    const float* doc_enc_W   = (const float*)d_in[3];
    const float* doc_enc_b   = (const float*)d_in[4];
    const float* slot_enc_W  = (const float*)d_in[5];
    const float* slot_enc_b  = (const float*)d_in[6];
    const float* doc_dec_W   = (const float*)d_in[7];
    const float* doc_dec_b   = (const float*)d_in[8];
    const float* slot_dec_W  = (const float*)d_in[9];
    const float* slot_dec_b  = (const float*)d_in[10];

    char* wsb = (char*)d_ws;
    __hip_bfloat16* ws        = (__hip_bfloat16*)wsb;
    int*            cnt       = (int*)(wsb + CNT_OFF_B);
    float*          sent_part = (float*)(wsb + SENTP_OFF_B);

    float* out = (float*)d_out;     // [0,4096): intents fp32; rest: slots fp32

    prep_kernel<<<89, 256, 0, stream>>>(slot_enc_W, slot_dec_W,
                                        doc_enc_W, doc_dec_W, ws, cnt);

    fused_kernel<<<512, 256, 0, stream>>>(
        token_ids, all_intents, emb_table, doc_enc_b,
        slot_enc_b, doc_dec_b, slot_dec_W, slot_dec_b,
        ws, sent_part, cnt,
        out, out + BATCH * NIN);
}

// Round 6
// 160.045 us; speedup vs baseline: 1.5722x; 1.2234x over previous
//
#include <hip/hip_runtime.h>
#include <hip/hip_bf16.h>

// MFMA fragment types (cdna_hip_programming.md §3)
typedef __attribute__((ext_vector_type(8))) short bf16x8;
typedef __attribute__((ext_vector_type(4))) float f32x4;

#define BATCH 64
#define SEQ   128
#define EMB   256
#define ENC   256
#define NIN   64
#define NSL   128

// packed-weight geometry in d_ws (bf16, B-fragment-major [kblk][n][j]):
//   w1p  : [32][256][8] (slot_enc_W)  off 0
//   w2p  : [32][128][8] (slot_dec_W)  off 65536
//   dw1p : [32][256][8] (doc_enc_W)   off 98304
//   dw2p : [32][ 64][8] (doc_dec_W)   off 163840
#define W1P_OFF   0
#define W2P_OFF   65536
#define DW1P_OFF  98304
#define DW2P_OFF  163840

// ---------------------------------------------------------------------------
// prep: transpose fp32 row-major weights into bf16 B-fragment-major layout.
// One thread per (kblk, n): 8 k-strided fp32 reads (each j-step coalesces
// across the n-lanes), one contiguous 16 B write.
// ---------------------------------------------------------------------------
#define PACK(W, NCOLS, DST, IDX) {                                            \
    const int n  = (IDX) & ((NCOLS) - 1);                                     \
    const int bk = (IDX) / (NCOLS);                                           \
    union { bf16x8 v; __hip_bfloat16 h[8]; } u;                               \
    _Pragma("unroll")                                                         \
    for (int j = 0; j < 8; ++j)                                               \
        u.h[j] = __float2bfloat16((W)[(bk * 8 + j) * (NCOLS) + n]);           \
    *(bf16x8*)((DST) + (size_t)(IDX) * 8) = u.v; }

__global__ __launch_bounds__(256) void prep_kernel(
    const float* __restrict__ slot_enc_W,   // [256][256]
    const float* __restrict__ slot_dec_W,   // [320][128] (k rows 0..255 used)
    const float* __restrict__ doc_enc_W,    // [256][256]
    const float* __restrict__ doc_dec_W,    // [256][64]
    __hip_bfloat16* __restrict__ ws)
{
    const int tid = blockIdx.x * 256 + threadIdx.x;   // 88*256 = 22528
    if (tid < 8192) {
        PACK(slot_enc_W, 256, ws + W1P_OFF,  tid);
    } else if (tid < 12288) {
        PACK(slot_dec_W, 128, ws + W2P_OFF,  tid - 8192);
    } else if (tid < 20480) {
        PACK(doc_enc_W,  256, ws + DW1P_OFF, tid - 12288);
    } else {
        PACK(doc_dec_W,   64, ws + DW2P_OFF, tid - 20480);
    }
}

static __device__ __forceinline__ bf16x8 cvt8(const float4 lo, const float4 hi) {
    union { bf16x8 v; __hip_bfloat16 h[8]; } u;
    u.h[0] = __float2bfloat16(lo.x); u.h[1] = __float2bfloat16(lo.y);
    u.h[2] = __float2bfloat16(lo.z); u.h[3] = __float2bfloat16(lo.w);
    u.h[4] = __float2bfloat16(hi.x); u.h[5] = __float2bfloat16(hi.y);
    u.h[6] = __float2bfloat16(hi.z); u.h[7] = __float2bfloat16(hi.w);
    return u.v;
}

// ---------------------------------------------------------------------------
// fused kernel, grid = 512 blocks exactly (2/CU, no ragged round).
//   every block   : slots path, 16 word-rows (row0 = blk*16), 4 waves.
//   blocks blk&7==0 additionally run the doc path for b = blk>>3 FIRST
//   (long-latency gather + two MFMA projections), so the serial doc chain
//   starts at t=0 and hides under the co-resident slots blocks.
//
// XCD-chunk swizzle (T1, bijective since 512 = 8*64): bid&7 selects the XCD
// (round-robin dispatch), so logical blocks [x*64, x*64+64) — i.e. 8 complete
// batches, including each batch's doc block — share XCD x. The doc block's
// 128-row re-gather then hits rows its sibling slots blocks pull into the
// same 4 MB L2 (8 batches x 128 KB = 1 MB << 4 MB).
//
// Doc MFMA trick: A-fragment rows are all identical (= sent[k] broadcast
// across l16), so every D row holds the same result; read reg 0.
// ---------------------------------------------------------------------------
__global__ __launch_bounds__(256) void fused_kernel(
    const int*   __restrict__ token_ids,
    const int*   __restrict__ all_intents,
    const float* __restrict__ emb_table,
    const float* __restrict__ doc_enc_b,
    const float* __restrict__ slot_enc_b,
    const float* __restrict__ doc_dec_b,
    const float* __restrict__ slot_dec_W,   // [320][128], fp32 (one-hot rows)
    const float* __restrict__ slot_dec_b,
    const __hip_bfloat16* __restrict__ ws,  // packed weights
    float* __restrict__ out_intent,         // fp32 [64][64]
    float* __restrict__ out_slots)          // fp32 [8192][128]
{
    __shared__ __align__(16) char smem[2 * 16 * 264 * 2];   // 16.9 KB

    const int bid  = blockIdx.x;
    const int blk  = ((bid & 7) << 6) | (bid >> 3);   // bijective XCD-chunk swizzle
    const int wave = threadIdx.x >> 6;
    const int lane = threadIdx.x & 63;
    const int l16  = lane & 15;
    const int quad = lane >> 4;

    const __hip_bfloat16* w1p  = ws + W1P_OFF;
    const __hip_bfloat16* w2p  = ws + W2P_OFF;
    const __hip_bfloat16* dw1p = ws + DW1P_OFF;
    const __hip_bfloat16* dw2p = ws + DW2P_OFF;

    if ((blk & 7) == 0) {
        // ================= doc path for b = blk>>3 =================
        float* red  = (float*)smem;            // [4][256]
        float* sent = (float*)(smem + 4096);   // [256] fp32
        float* senc = (float*)(smem + 5120);   // [256] fp32

        const int b  = blk >> 3;
        const int t  = threadIdx.x;
        const int* toks = token_ids + b * SEQ;

        // mean over 128 token rows (wave -> 32 rows, lane -> 16 B slice)
        float4 accv = make_float4(0.f, 0.f, 0.f, 0.f);
        #pragma unroll 8
        for (int i = 0; i < 32; ++i) {
            const long tok = toks[wave * 32 + i];
            const float4 v = *(const float4*)(emb_table + tok * EMB + lane * 4);
            accv.x += v.x; accv.y += v.y; accv.z += v.z; accv.w += v.w;
        }
        *(float4*)(&red[wave * 256 + lane * 4]) = accv;
        __syncthreads();

        sent[t] = (red[t] + red[256 + t] + red[512 + t] + red[768 + t])
                  * (1.0f / 128.0f);
        __syncthreads();

        // doc encoder: senc = relu(sent @ W + b), wave owns 64 cols
        f32x4 dacc[4];
        #pragma unroll
        for (int nt = 0; nt < 4; ++nt) dacc[nt] = (f32x4){0.f, 0.f, 0.f, 0.f};

        #pragma unroll
        for (int ks = 0; ks < 8; ++ks) {
            const float* sp = sent + ks * 32 + quad * 8;
            const bf16x8 a = cvt8(*(const float4*)sp, *(const float4*)(sp + 4));
            const int kblk = ks * 4 + quad;
            #pragma unroll
            for (int nt = 0; nt < 4; ++nt) {
                const int n = wave * 64 + nt * 16 + l16;
                const bf16x8 bf = *(const bf16x8*)(dw1p + ((size_t)kblk * 256 + n) * 8);
                dacc[nt] = __builtin_amdgcn_mfma_f32_16x16x32_bf16(a, bf, dacc[nt], 0, 0, 0);
            }
        }
        if (quad == 0) {
            #pragma unroll
            for (int nt = 0; nt < 4; ++nt) {
                const int col = wave * 64 + nt * 16 + l16;
                senc[col] = fmaxf(dacc[nt][0] + doc_enc_b[col], 0.f);
            }
        }
        __syncthreads();

        // doc decoder: intent = senc @ Wd + b, wave owns 16 cols
        f32x4 iacc = (f32x4){0.f, 0.f, 0.f, 0.f};
        #pragma unroll
        for (int ks = 0; ks < 8; ++ks) {
            const float* sp = senc + ks * 32 + quad * 8;
            const bf16x8 a = cvt8(*(const float4*)sp, *(const float4*)(sp + 4));
            const int kblk = ks * 4 + quad;
            const int n = wave * 16 + l16;
            const bf16x8 bf = *(const bf16x8*)(dw2p + ((size_t)kblk * 64 + n) * 8);
            iacc = __builtin_amdgcn_mfma_f32_16x16x32_bf16(a, bf, iacc, 0, 0, 0);
        }
        if (quad == 0)
            out_intent[b * NIN + wave * 16 + l16] = iacc[0] + doc_dec_b[wave * 16 + l16];
        __syncthreads();   // senc/LDS reads done before slots phase overwrites
    }

    // ================= slots path (all 512 blocks) =================
    __hip_bfloat16* lds_emb = (__hip_bfloat16*)smem;            // [16][264]
    __hip_bfloat16* lds_we  = (__hip_bfloat16*)(smem + 16 * 264 * 2);

    const int row0 = blk * 16;

    // ---------------- stage 0: gather 16 token rows into LDS ----------
    #pragma unroll
    for (int i = 0; i < 4; ++i) {
        const int idx = i * 256 + threadIdx.x;    // 0..1023
        const int r   = idx >> 6;                 // row 0..15
        const int c4  = idx & 63;                 // float4 within row
        const long tok = token_ids[row0 + r];
        const float4 v = *(const float4*)(emb_table + tok * EMB + c4 * 4);
        union { ushort4 s; __hip_bfloat16 h[4]; } u;
        u.h[0] = __float2bfloat16(v.x); u.h[1] = __float2bfloat16(v.y);
        u.h[2] = __float2bfloat16(v.z); u.h[3] = __float2bfloat16(v.w);
        *(ushort4*)(lds_emb + r * 264 + c4 * 4) = u.s;
    }
    __syncthreads();

    // ---------------- stage 1: word_enc = relu(emb @ W1 + b1) ----------
    f32x4 acc[4];
    #pragma unroll
    for (int nt = 0; nt < 4; ++nt) acc[nt] = (f32x4){0.f, 0.f, 0.f, 0.f};

    const int nbase1 = wave * 64;
    #pragma unroll
    for (int ks = 0; ks < 8; ++ks) {
        const bf16x8 a0 = *(const bf16x8*)(lds_emb + l16 * 264 + ks * 32 + quad * 8);
        const int kblk = ks * 4 + quad;
        #pragma unroll
        for (int nt = 0; nt < 4; ++nt) {
            const int n = nbase1 + nt * 16 + l16;
            const bf16x8 bf = *(const bf16x8*)(w1p + ((size_t)kblk * 256 + n) * 8);
            acc[nt] = __builtin_amdgcn_mfma_f32_16x16x32_bf16(a0, bf, acc[nt], 0, 0, 0);
        }
    }

    #pragma unroll
    for (int nt = 0; nt < 4; ++nt) {
        const int col = nbase1 + nt * 16 + l16;
        const float bias = slot_enc_b[col];
        #pragma unroll
        for (int r = 0; r < 4; ++r) {
            const int row = quad * 4 + r;   // D: col=lane&15, row=quad*4+reg
            lds_we[row * 264 + col] =
                __float2bfloat16(fmaxf(acc[nt][r] + bias, 0.f));
        }
    }
    __syncthreads();

    // ---------------- stage 2: slots = word_enc @ W2 ----------
    f32x4 acc2[2];
    #pragma unroll
    for (int nt = 0; nt < 2; ++nt) acc2[nt] = (f32x4){0.f, 0.f, 0.f, 0.f};

    const int nbase2 = wave * 32;
    #pragma unroll
    for (int ks = 0; ks < 8; ++ks) {
        const bf16x8 a0 = *(const bf16x8*)(lds_we + l16 * 264 + ks * 32 + quad * 8);
        const int kblk = ks * 4 + quad;
        #pragma unroll
        for (int nt = 0; nt < 2; ++nt) {
            const int n = nbase2 + nt * 16 + l16;
            const bf16x8 bf = *(const bf16x8*)(w2p + ((size_t)kblk * 128 + n) * 8);
            acc2[nt] = __builtin_amdgcn_mfma_f32_16x16x32_bf16(a0, bf, acc2[nt], 0, 0, 0);
        }
    }

    // epilogue: + slot_dec_b + slot_dec_W[256 + intent[b]] row, fp32 store
    const int intent = all_intents[blk >> 3];
    const float* hotrow = slot_dec_W + (long)(256 + intent) * NSL;

    #pragma unroll
    for (int nt = 0; nt < 2; ++nt) {
        const int col = nbase2 + nt * 16 + l16;
        const float add = slot_dec_b[col] + hotrow[col];
        #pragma unroll
        for (int r = 0; r < 4; ++r) {
            const int row = quad * 4 + r;
            out_slots[(long)(row0 + row) * NSL + col] = acc2[nt][r] + add;
        }
    }
}

// ---------------------------------------------------------------------------
extern "C" void kernel_launch(void* const* d_in, const int* in_sizes, int n_in,
                              void* d_out, int out_size, void* d_ws, size_t ws_size,
                              hipStream_t stream) {
    const int*   token_ids   = (const int*)d_in[0];
    const int*   all_intents = (const int*)d_in[1];
    const float* emb_table   = (const float*)d_in[2];
    const float* doc_enc_W   = (const float*)d_in[3];
    const float* doc_enc_b   = (const float*)d_in[4];
    const float* slot_enc_W  = (const float*)d_in[5];
    const float* slot_enc_b  = (const float*)d_in[6];
    const float* doc_dec_W   = (const float*)d_in[7];
    const float* doc_dec_b   = (const float*)d_in[8];
    const float* slot_dec_W  = (const float*)d_in[9];
    const float* slot_dec_b  = (const float*)d_in[10];

    __hip_bfloat16* ws = (__hip_bfloat16*)d_ws;
    float* out = (float*)d_out;     // [0,4096): intents fp32; rest: slots fp32

    prep_kernel<<<88, 256, 0, stream>>>(slot_enc_W, slot_dec_W,
                                        doc_enc_W, doc_dec_W, ws);

    fused_kernel<<<512, 256, 0, stream>>>(
        token_ids, all_intents, emb_table, doc_enc_b,
        slot_enc_b, doc_dec_b, slot_dec_W, slot_dec_b,
        ws, out, out + BATCH * NIN);
}